// Round 4
// baseline (111.356 us; speedup 1.0000x reference)
//
#include <hip/hip_runtime.h>
#include <math.h>

// Chamfer loss, B=32, N=2048, 3 used components.
// R3: MFMA. d2[n][m] = x2[n] + y2[m] - 2 p.q is a K=16 GEMM with split-bf16
// operands (c = hi + lo, both bf16 -> ~2^-17 relative repr):
//   A(p) = [x2h,x2l, 1,1, -2ph(xyz), -2ph(xyz), -2pl(xyz), -2pl(xyz)]
//   B(q) = [1,1, y2h,y2l,  qh(xyz),   ql(xyz),   qh(xyz),   ql(xyz)]
// so one v_mfma_f32_16x16x32_bf16 emits 256 exact-ish d2 values (K slots
// 16..31 zero). A/B use identical K-placement -> result invariant to the HW
// K-chunk permutation. C layout: col=lane&15, row=(lane>>4)*4+reg (verified).
// Epilogue: 8 VALU mins per MFMA into row/col running minima, shfl/LDS
// reduce, global atomicMin on uint-cast clamped d2; sum kernel finishes.

#define NPTS   2048
#define NBATCH 32
#define NTOT   (2 * NBATCH * NPTS)
#define EPSF   1e-16f
#define BIGF   3.4e38f

typedef short bf16x8 __attribute__((ext_vector_type(8)));
typedef float f32x4  __attribute__((ext_vector_type(4)));

__device__ __forceinline__ short f2b(float f) {          // fp32 -> bf16 RNE
    unsigned u = __float_as_uint(f);
    return (short)((u + 0x7FFFu + ((u >> 16) & 1u)) >> 16);
}
__device__ __forceinline__ float b2f(short h) {
    return __uint_as_float(((unsigned)(unsigned short)h) << 16);
}

__global__ __launch_bounds__(256) void chamfer_mfma_kernel(
    const float* __restrict__ P, const float* __restrict__ Q,
    unsigned int* __restrict__ ws)
{
    __shared__ short sA[256 * 16];     // p-side slots, 8 KB
    __shared__ short sB[256 * 16];     // q-side slots, 8 KB
    __shared__ float scol[4][256];     // per-wave col partials, 4 KB

    const int tid  = threadIdx.x;
    const int w    = tid >> 6;         // wave 0..3
    const int lane = tid & 63;
    const int l15  = lane & 15;
    const int kc   = lane >> 4;        // K-chunk 0..3 (2,3 are zero slots)
    const int bi   = blockIdx.x;       // p row-chunk
    const int bj   = blockIdx.y;       // q col-chunk
    const int b    = blockIdx.z;       // batch

    // ---- stage: thread t builds slots for p-point t and q-point t of tile
    {
        float4 pv = ((const float4*)P)[(size_t)b * NPTS + bi * 256 + tid];
        float4 qv = ((const float4*)Q)[(size_t)b * NPTS + bj * 256 + tid];
        const short one = f2b(1.0f);

        float px = pv.y, py = pv.z, pz = pv.w;
        float x2 = px*px + py*py + pz*pz;
        short x2h = f2b(x2),  x2l = f2b(x2 - b2f(x2h));
        short phx = f2b(px),  plx = f2b(px - b2f(phx));
        short phy = f2b(py),  ply = f2b(py - b2f(phy));
        short phz = f2b(pz),  plz = f2b(pz - b2f(phz));
        short mhx = f2b(-2.f * b2f(phx)), mlx = f2b(-2.f * b2f(plx));
        short mhy = f2b(-2.f * b2f(phy)), mly = f2b(-2.f * b2f(ply));
        short mhz = f2b(-2.f * b2f(phz)), mlz = f2b(-2.f * b2f(plz));
        __align__(16) short a[16] = { x2h, x2l, one, one,
                                      mhx, mhy, mhz, mhx, mhy, mhz,
                                      mlx, mly, mlz, mlx, mly, mlz };

        float qx = qv.y, qy = qv.z, qz = qv.w;
        float y2 = qx*qx + qy*qy + qz*qz;
        short y2h = f2b(y2),  y2l = f2b(y2 - b2f(y2h));
        short qhx = f2b(qx),  qlx = f2b(qx - b2f(qhx));
        short qhy = f2b(qy),  qly = f2b(qy - b2f(qhy));
        short qhz = f2b(qz),  qlz = f2b(qz - b2f(qhz));
        __align__(16) short bb[16] = { one, one, y2h, y2l,
                                       qhx, qhy, qhz, qlx, qly, qlz,
                                       qhx, qhy, qhz, qlx, qly, qlz };

        *(uint4*)&sA[tid * 16]     = *(const uint4*)&a[0];
        *(uint4*)&sA[tid * 16 + 8] = *(const uint4*)&a[8];
        *(uint4*)&sB[tid * 16]     = *(const uint4*)&bb[0];
        *(uint4*)&sB[tid * 16 + 8] = *(const uint4*)&bb[8];
    }
    __syncthreads();

    // ---- A fragments: wave w owns rows [w*64, w*64+64) = 4 row-tiles
    const bf16x8 zf = {0, 0, 0, 0, 0, 0, 0, 0};
    bf16x8 Af[4];
    #pragma unroll
    for (int r = 0; r < 4; ++r) {
        const int pt = w * 64 + r * 16 + l15;
        Af[r] = (kc < 2) ? *(const bf16x8*)&sA[pt * 16 + kc * 8] : zf;
    }

    float rowmin[4][4], colmin[16];
    #pragma unroll
    for (int r = 0; r < 4; ++r)
        #pragma unroll
        for (int g = 0; g < 4; ++g) rowmin[r][g] = BIGF;
    #pragma unroll
    for (int j = 0; j < 16; ++j) colmin[j] = BIGF;

    // ---- main loop: 16 col-tiles x 4 row-tiles = 64 MFMAs per wave
    #pragma unroll
    for (int j = 0; j < 16; ++j) {
        const int pt = j * 16 + l15;
        bf16x8 Bf = (kc < 2) ? *(const bf16x8*)&sB[pt * 16 + kc * 8] : zf;
        #pragma unroll
        for (int r = 0; r < 4; ++r) {
            f32x4 c = {0.f, 0.f, 0.f, 0.f};
            c = __builtin_amdgcn_mfma_f32_16x16x32_bf16(Af[r], Bf, c, 0, 0, 0);
            rowmin[r][0] = fminf(rowmin[r][0], c[0]);
            rowmin[r][1] = fminf(rowmin[r][1], c[1]);
            rowmin[r][2] = fminf(rowmin[r][2], c[2]);
            rowmin[r][3] = fminf(rowmin[r][3], c[3]);
            colmin[j] = fminf(colmin[j],
                              fminf(fminf(c[0], c[1]), fminf(c[2], c[3])));
        }
    }

    // ---- row minima: reduce across col-classes (lane bits 0..3), publish
    #pragma unroll
    for (int r = 0; r < 4; ++r)
        #pragma unroll
        for (int g = 0; g < 4; ++g) {
            float v = rowmin[r][g];
            v = fminf(v, __shfl_xor(v, 1));
            v = fminf(v, __shfl_xor(v, 2));
            v = fminf(v, __shfl_xor(v, 4));
            v = fminf(v, __shfl_xor(v, 8));
            rowmin[r][g] = v;
        }
    if (l15 == 0) {
        #pragma unroll
        for (int r = 0; r < 4; ++r)
            #pragma unroll
            for (int g = 0; g < 4; ++g) {
                const int row = bi * 256 + w * 64 + r * 16 + (lane >> 4) * 4 + g;
                float d2 = fmaxf(rowmin[r][g], 0.f);
                atomicMin(&ws[b * NPTS + row], __float_as_uint(d2));
            }
    }

    // ---- col minima: reduce across row-groups (lane bits 4,5), cross-wave
    #pragma unroll
    for (int j = 0; j < 16; ++j) {
        float v = colmin[j];
        v = fminf(v, __shfl_xor(v, 16));
        v = fminf(v, __shfl_xor(v, 32));
        colmin[j] = v;
    }
    if (lane < 16) {
        #pragma unroll
        for (int j = 0; j < 16; ++j) scol[w][j * 16 + lane] = colmin[j];
    }
    __syncthreads();
    {
        float v = fminf(fminf(scol[0][tid], scol[1][tid]),
                        fminf(scol[2][tid], scol[3][tid]));
        float d2 = fmaxf(v, 0.f);
        atomicMin(&ws[NBATCH * NPTS + b * NPTS + bj * 256 + tid],
                  __float_as_uint(d2));
    }
}

__global__ __launch_bounds__(256) void chamfer_sum_kernel(
    const unsigned int* __restrict__ ws, float* __restrict__ out)
{
    __shared__ float rbuf[4];
    const int tid = threadIdx.x;
    const int i0  = blockIdx.x * 256 + tid;

    float s = 0.f;
    for (int i = i0; i < NTOT; i += gridDim.x * 256)
        s += sqrtf(__uint_as_float(ws[i]) + EPSF);

    #pragma unroll
    for (int off = 32; off > 0; off >>= 1) s += __shfl_down(s, off);
    if ((tid & 63) == 0) rbuf[tid >> 6] = s;
    __syncthreads();
    if (tid == 0)
        atomicAdd(out, 0.5f * ((rbuf[0] + rbuf[1]) + (rbuf[2] + rbuf[3])));
}

extern "C" void kernel_launch(void* const* d_in, const int* in_sizes, int n_in,
                              void* d_out, int out_size, void* d_ws, size_t ws_size,
                              hipStream_t stream) {
    const float* P = (const float*)d_in[0];   // p[0] = first 32*2048*4 floats
    const float* Q = (const float*)d_in[1];
    float* out = (float*)d_out;
    unsigned int* ws = (unsigned int*)d_ws;

    // sentinel 0x7F7F7F7F = 3.39e38f (uint-monotone for nonneg floats)
    hipMemsetAsync(ws, 0x7F, (size_t)NTOT * sizeof(unsigned int), stream);
    hipMemsetAsync(out, 0, sizeof(float), stream);

    dim3 grid(NPTS / 256, NPTS / 256, NBATCH);   // 8 x 8 x 32 = 2048 blocks
    chamfer_mfma_kernel<<<grid, 256, 0, stream>>>(P, Q, ws);

    chamfer_sum_kernel<<<128, 256, 0, stream>>>(ws, out);
}

// Round 5
// 110.840 us; speedup vs baseline: 1.0047x; 1.0047x over previous
//
#include <hip/hip_runtime.h>
#include <math.h>

// Chamfer loss, B=32, N=2048, 3 used components.
// R4: MFMA (d2 as K=16 GEMM with split-bf16 operands, slots verified in R3;
// A/B share K-placement so HW K-permutation cancels). Fixes vs R3:
//  - LDS fragment layout [kchunk][point]x16B -> frag loads contiguous in l15
//    (<=2-way bank alias = free) instead of 4-way conflicts.
//  - col partials reduced & spilled to scol INSIDE the j loop (2 shfl + 1
//    LDS write) -> no colmin[16] register array; only rowmin[4][4] persists.
//  - j-pair batching: 8 independent MFMAs in flight, consumed with v_min3.
// Epilogue: uint-atomicMin of clamped d2 into ws; sum kernel finishes.

#define NPTS   2048
#define NBATCH 32
#define NTOT   (2 * NBATCH * NPTS)
#define EPSF   1e-16f
#define BIGF   3.4e38f

typedef short bf16x8 __attribute__((ext_vector_type(8)));
typedef float f32x4  __attribute__((ext_vector_type(4)));

__device__ __forceinline__ short f2b(float f) {          // fp32 -> bf16 RNE
    unsigned u = __float_as_uint(f);
    return (short)((u + 0x7FFFu + ((u >> 16) & 1u)) >> 16);
}
__device__ __forceinline__ float b2f(short h) {
    return __uint_as_float(((unsigned)(unsigned short)h) << 16);
}
__device__ __forceinline__ float min3f(float a, float b, float c) {
    return fminf(fminf(a, b), c);    // -> v_min3_f32
}

__global__ __launch_bounds__(256) void chamfer_mfma_kernel(
    const float* __restrict__ P, const float* __restrict__ Q,
    unsigned int* __restrict__ ws)
{
    __shared__ short sA[2][256 * 8];   // [kchunk][point*8shorts] = 8 KB
    __shared__ short sB[2][256 * 8];   // 8 KB
    __shared__ float scol[4][256];     // 4 KB

    const int tid  = threadIdx.x;
    const int w    = tid >> 6;
    const int lane = tid & 63;
    const int l15  = lane & 15;
    const int kc   = lane >> 4;        // K-chunk 0..3 (2,3 are zero slots)
    const int bi   = blockIdx.x;
    const int bj   = blockIdx.y;
    const int b    = blockIdx.z;

    // ---- stage: thread t builds the 16 K-slots for p-point t, q-point t
    {
        float4 pv = ((const float4*)P)[(size_t)b * NPTS + bi * 256 + tid];
        float4 qv = ((const float4*)Q)[(size_t)b * NPTS + bj * 256 + tid];
        const short one = f2b(1.0f);

        float px = pv.y, py = pv.z, pz = pv.w;
        float x2 = px * px + py * py + pz * pz;
        short x2h = f2b(x2); short x2l = f2b(x2 - b2f(x2h));
        float tx = -2.f * px; short mhx = f2b(tx); short mlx = f2b(tx - b2f(mhx));
        float ty = -2.f * py; short mhy = f2b(ty); short mly = f2b(ty - b2f(mhy));
        float tz = -2.f * pz; short mhz = f2b(tz); short mlz = f2b(tz - b2f(mhz));
        __align__(16) short a0[8] = { x2h, x2l, one, one, mhx, mhy, mhz, mhx };
        __align__(16) short a1[8] = { mhy, mhz, mlx, mly, mlz, mlx, mly, mlz };

        float qx = qv.y, qy = qv.z, qz = qv.w;
        float y2 = qx * qx + qy * qy + qz * qz;
        short y2h = f2b(y2); short y2l = f2b(y2 - b2f(y2h));
        short qhx = f2b(qx), qlx = f2b(qx - b2f(qhx));
        short qhy = f2b(qy), qly = f2b(qy - b2f(qhy));
        short qhz = f2b(qz), qlz = f2b(qz - b2f(qhz));
        __align__(16) short b0[8] = { one, one, y2h, y2l, qhx, qhy, qhz, qlx };
        __align__(16) short b1[8] = { qly, qlz, qhx, qhy, qhz, qlx, qly, qlz };

        *(uint4*)&sA[0][tid * 8] = *(const uint4*)a0;   // k = 0..7
        *(uint4*)&sA[1][tid * 8] = *(const uint4*)a1;   // k = 8..15
        *(uint4*)&sB[0][tid * 8] = *(const uint4*)b0;
        *(uint4*)&sB[1][tid * 8] = *(const uint4*)b1;
    }
    __syncthreads();

    // ---- A fragments: wave w owns rows [w*64, w*64+64)
    const bf16x8 zf = {0, 0, 0, 0, 0, 0, 0, 0};
    bf16x8 Af[4];
    #pragma unroll
    for (int r = 0; r < 4; ++r) {
        const int pt = w * 64 + r * 16 + l15;
        Af[r] = (kc < 2) ? *(const bf16x8*)&sA[kc][pt * 8] : zf;
    }

    float rowmin[4][4];
    #pragma unroll
    for (int r = 0; r < 4; ++r)
        #pragma unroll
        for (int g = 0; g < 4; ++g) rowmin[r][g] = BIGF;

    // ---- main loop: j-pairs, 8 independent MFMAs in flight
    for (int jp = 0; jp < 8; ++jp) {
        const int j0 = 2 * jp, j1 = 2 * jp + 1;
        bf16x8 Bf0 = (kc < 2) ? *(const bf16x8*)&sB[kc][(j0 * 16 + l15) * 8] : zf;
        bf16x8 Bf1 = (kc < 2) ? *(const bf16x8*)&sB[kc][(j1 * 16 + l15) * 8] : zf;

        f32x4 c0[4], c1[4];
        #pragma unroll
        for (int r = 0; r < 4; ++r) {
            f32x4 z = {0.f, 0.f, 0.f, 0.f};
            c0[r] = __builtin_amdgcn_mfma_f32_16x16x32_bf16(Af[r], Bf0, z, 0, 0, 0);
            c1[r] = __builtin_amdgcn_mfma_f32_16x16x32_bf16(Af[r], Bf1, z, 0, 0, 0);
        }

        float col0 = BIGF, col1 = BIGF;
        #pragma unroll
        for (int r = 0; r < 4; ++r) {
            rowmin[r][0] = min3f(rowmin[r][0], c0[r][0], c1[r][0]);
            rowmin[r][1] = min3f(rowmin[r][1], c0[r][1], c1[r][1]);
            rowmin[r][2] = min3f(rowmin[r][2], c0[r][2], c1[r][2]);
            rowmin[r][3] = min3f(rowmin[r][3], c0[r][3], c1[r][3]);
            col0 = min3f(col0, fminf(c0[r][0], c0[r][1]),
                               fminf(c0[r][2], c0[r][3]));
            col1 = min3f(col1, fminf(c1[r][0], c1[r][1]),
                               fminf(c1[r][2], c1[r][3]));
        }

        // col partial: reduce across row-groups (lane bits 4,5), spill to LDS
        col0 = fminf(col0, __shfl_xor(col0, 16));
        col0 = fminf(col0, __shfl_xor(col0, 32));
        col1 = fminf(col1, __shfl_xor(col1, 16));
        col1 = fminf(col1, __shfl_xor(col1, 32));
        if (lane < 16) {
            scol[w][j0 * 16 + lane] = col0;
            scol[w][j1 * 16 + lane] = col1;
        }
    }

    // ---- row minima: reduce across col-classes (lane bits 0..3), publish
    #pragma unroll
    for (int r = 0; r < 4; ++r)
        #pragma unroll
        for (int g = 0; g < 4; ++g) {
            float v = rowmin[r][g];
            v = fminf(v, __shfl_xor(v, 1));
            v = fminf(v, __shfl_xor(v, 2));
            v = fminf(v, __shfl_xor(v, 4));
            v = fminf(v, __shfl_xor(v, 8));
            rowmin[r][g] = v;
        }
    if (l15 == 0) {
        #pragma unroll
        for (int r = 0; r < 4; ++r)
            #pragma unroll
            for (int g = 0; g < 4; ++g) {
                const int row = bi * 256 + w * 64 + r * 16 + (lane >> 4) * 4 + g;
                float d2 = fmaxf(rowmin[r][g], 0.f);
                atomicMin(&ws[b * NPTS + row], __float_as_uint(d2));
            }
    }

    // ---- col minima: combine the 4 per-wave partials, publish
    __syncthreads();
    {
        float v = fminf(fminf(scol[0][tid], scol[1][tid]),
                        fminf(scol[2][tid], scol[3][tid]));
        float d2 = fmaxf(v, 0.f);
        atomicMin(&ws[NBATCH * NPTS + b * NPTS + bj * 256 + tid],
                  __float_as_uint(d2));
    }
}

__global__ __launch_bounds__(256) void chamfer_sum_kernel(
    const unsigned int* __restrict__ ws, float* __restrict__ out)
{
    __shared__ float rbuf[4];
    const int tid = threadIdx.x;
    const int i0  = blockIdx.x * 256 + tid;

    float s = 0.f;
    for (int i = i0; i < NTOT; i += gridDim.x * 256)
        s += sqrtf(__uint_as_float(ws[i]) + EPSF);

    #pragma unroll
    for (int off = 32; off > 0; off >>= 1) s += __shfl_down(s, off);
    if ((tid & 63) == 0) rbuf[tid >> 6] = s;
    __syncthreads();
    if (tid == 0)
        atomicAdd(out, 0.5f * ((rbuf[0] + rbuf[1]) + (rbuf[2] + rbuf[3])));
}

extern "C" void kernel_launch(void* const* d_in, const int* in_sizes, int n_in,
                              void* d_out, int out_size, void* d_ws, size_t ws_size,
                              hipStream_t stream) {
    const float* P = (const float*)d_in[0];   // p[0] = first 32*2048*4 floats
    const float* Q = (const float*)d_in[1];
    float* out = (float*)d_out;
    unsigned int* ws = (unsigned int*)d_ws;

    // sentinel 0x7F7F7F7F = 3.39e38f (uint-monotone for nonneg floats)
    hipMemsetAsync(ws, 0x7F, (size_t)NTOT * sizeof(unsigned int), stream);
    hipMemsetAsync(out, 0, sizeof(float), stream);

    dim3 grid(NPTS / 256, NPTS / 256, NBATCH);   // 8 x 8 x 32 = 2048 blocks
    chamfer_mfma_kernel<<<grid, 256, 0, stream>>>(P, Q, ws);

    chamfer_sum_kernel<<<128, 256, 0, stream>>>(ws, out);
}